// Round 2
// baseline (125.034 us; speedup 1.0000x reference)
//
#include <hip/hip_runtime.h>
#include <hip/hip_bf16.h>

typedef __bf16 bf16;
typedef bf16 bf16x4 __attribute__((ext_vector_type(4)));
typedef bf16 bf16x8 __attribute__((ext_vector_type(8)));
typedef float floatx4 __attribute__((ext_vector_type(4)));

#define GLOBAL_AS __attribute__((address_space(1)))
#define LDS_AS __attribute__((address_space(3)))

// ---------------------------------------------------------------------------
// f32 -> bf16 conversion for x, w_qkv, w_proj (float4 granular).
// R9/R10 A/B test: cvt3 + bf16-async GEMM1 beats f32-direct GEMM1 by ~10 us.
// ---------------------------------------------------------------------------
__global__ __launch_bounds__(256)
void cvt3_f32_bf16(const float* __restrict__ s0, const float* __restrict__ s1,
                   const float* __restrict__ s2, bf16* __restrict__ d0,
                   bf16* __restrict__ d1, bf16* __restrict__ d2,
                   int n0, int n1, int n2)
{
    int t = blockIdx.x * blockDim.x + threadIdx.x;
    const float* s; bf16* d; int i;
    if (t < n0)                { s = s0; d = d0; i = t; }
    else if (t < n0 + n1)      { s = s1; d = d1; i = t - n0; }
    else if (t < n0 + n1 + n2) { s = s2; d = d2; i = t - n0 - n1; }
    else return;
    float4 v = ((const float4*)s)[i];
    bf16x4 o = { (bf16)v.x, (bf16)v.y, (bf16)v.z, (bf16)v.w };
    ((bf16x4*)d)[i] = o;
}

// ---------------------------------------------------------------------------
// GEMM: C[m][n] = sum_k A[m][k] * W[n][k]  (+ bias[n] if bias != null)
// Compile-time shapes. Tile TM x 128, 256 thr (4 waves).
// R12: BK=32 -> BK=64. The 2-barrier structure's documented stall is the
// full vmcnt(0)+lgkmcnt(0) drain before each s_barrier (~20% of time);
// halving the number of K-iterations (12 vs 24 for K=768) halves the drain
// count while keeping the same frag-register footprint (two kk-passes of
// 8 live fragments). LDS: TM=128 -> 32KB/block, TM=64 -> 24KB/block; still
// >= 2 blocks/CU. Staging issues 8 async global_load_lds per wave per iter
// (vs 4) -> more in-flight loads per drain.
// R11: XCD-chunked block swizzle (T1), bijective since gridDim.x % 8 == 0.
// ---------------------------------------------------------------------------
template<typename CT, bool AF32, bool WF32, int TM, int M, int N, int K,
         int LDA, int LDC>
__global__ __launch_bounds__(256, 2)
void gemm_bt(const void* __restrict__ Av, const void* __restrict__ Wv,
             CT* __restrict__ C, const float* __restrict__ bias)
{
    constexpr int MI = TM / 32;          // acc rows per wave (4 or 2)
    __shared__ __align__(16) bf16 As[TM * 64];
    __shared__ __align__(16) bf16 Bs[128 * 64];

    const int tid  = threadIdx.x;
    const int lane = tid & 63;
    const int wave = tid >> 6;

    // XCD swizzle (T1)
    const int lin = blockIdx.y * gridDim.x + blockIdx.x;
    const int ch  = gridDim.x >> 3;
    const int xcd = lin & 7;
    const int rr  = lin >> 3;
    const int bx  = xcd * ch + (rr % ch);
    const int by  = rr / ch;

    const int row0 = bx * TM;
    const int col0 = by * 128;

    const int wm = (wave & 1) * (TM / 2);
    const int wn = (wave >> 1) * 64;

    floatx4 acc[MI][4] = {};

    const int fr = lane & 15;
    const int fk = (lane >> 4) * 8;

    const int lr = lane >> 3;        // async staging: row within 8-row chunk
    const int lk = (lane & 7) * 8;   //                k offset within row

    for (int k0 = 0; k0 < K; k0 += 64) {
        // ---- A staging (TM x 64 tile) ----
        if (AF32) {
            constexpr int NV = TM * 8;             // # of 8-elem vectors
            #pragma unroll
            for (int c = 0; c < NV / 256; ++c) {
                const int idx = tid + c * 256;
                const int r   = idx >> 3;
                const int cb  = (idx & 7) * 8;
                const float4* g = (const float4*)((const float*)Av
                                   + (size_t)(row0 + r) * LDA + k0 + cb);
                float4 g0 = g[0], g1 = g[1];
                bf16x8 va;
                va[0]=(bf16)g0.x; va[1]=(bf16)g0.y; va[2]=(bf16)g0.z; va[3]=(bf16)g0.w;
                va[4]=(bf16)g1.x; va[5]=(bf16)g1.y; va[6]=(bf16)g1.z; va[7]=(bf16)g1.w;
                *(bf16x8*)(As + r * 64 + cb) = va;
            }
        } else {
            constexpr int CAW = TM / 32;           // A chunks per wave
            #pragma unroll
            for (int c = 0; c < CAW; ++c) {
                const int chunk = wave * CAW + c;
                const int r = chunk * 8 + lr;
                const bf16* gA = (const bf16*)Av + (size_t)(row0 + r) * LDA + k0 + lk;
                __builtin_amdgcn_global_load_lds((const GLOBAL_AS void*)gA,
                                                 (LDS_AS void*)(As + chunk * 512),
                                                 16, 0, 0);
            }
        }
        // ---- W staging (always 128x64 tile = 16 chunks, 4 per wave) ----
        if (WF32) {
            #pragma unroll
            for (int c = 0; c < 4; ++c) {
                const int idx = tid + c * 256;
                const int r   = idx >> 3;
                const int cb  = (idx & 7) * 8;
                const float4* g = (const float4*)((const float*)Wv
                                   + (size_t)(col0 + r) * K + k0 + cb);
                float4 g0 = g[0], g1 = g[1];
                bf16x8 vw;
                vw[0]=(bf16)g0.x; vw[1]=(bf16)g0.y; vw[2]=(bf16)g0.z; vw[3]=(bf16)g0.w;
                vw[4]=(bf16)g1.x; vw[5]=(bf16)g1.y; vw[6]=(bf16)g1.z; vw[7]=(bf16)g1.w;
                *(bf16x8*)(Bs + r * 64 + cb) = vw;
            }
        } else {
            #pragma unroll
            for (int c = 0; c < 4; ++c) {
                const int chunk = wave * 4 + c;
                const int r = chunk * 8 + lr;
                const bf16* gB = (const bf16*)Wv + (size_t)(col0 + r) * K + k0 + lk;
                __builtin_amdgcn_global_load_lds((const GLOBAL_AS void*)gB,
                                                 (LDS_AS void*)(Bs + chunk * 512),
                                                 16, 0, 0);
            }
        }
        __syncthreads();

        // two kk-passes: 8 live fragments each, 16 MFMA per pass
        #pragma unroll
        for (int kk = 0; kk < 2; ++kk) {
            bf16x8 af[MI], bfr[4];
            #pragma unroll
            for (int i = 0; i < MI; ++i)
                af[i]  = *(const bf16x8*)(As + (wm + i * 16 + fr) * 64 + kk * 32 + fk);
            #pragma unroll
            for (int j = 0; j < 4; ++j)
                bfr[j] = *(const bf16x8*)(Bs + (wn + j * 16 + fr) * 64 + kk * 32 + fk);
            #pragma unroll
            for (int i = 0; i < MI; ++i)
                #pragma unroll
                for (int j = 0; j < 4; ++j)
                    acc[i][j] = __builtin_amdgcn_mfma_f32_16x16x32_bf16(
                        af[i], bfr[j], acc[i][j], 0, 0, 0);
        }

        __syncthreads();
    }

    const int fc  = lane & 15;
    const int fr4 = (lane >> 4) * 4;
    #pragma unroll
    for (int i = 0; i < MI; ++i) {
        #pragma unroll
        for (int j = 0; j < 4; ++j) {
            const int col = col0 + wn + j * 16 + fc;
            const float b = bias ? bias[col] : 0.0f;
            #pragma unroll
            for (int r = 0; r < 4; ++r) {
                const int row = row0 + wm + i * 16 + fr4 + r;
                C[(size_t)row * LDC + col] = (CT)(acc[i][j][r] + b);
            }
        }
    }
}

// ---------------------------------------------------------------------------
// MFMA local-window attention. One wave per (b, h, 16-row i-tile).
// R11 (verified): wave-private LDS (no block barriers), K B-fragments loaded
// directly from L2-hot qkv, Vt transpose XOR-swizzled (4-way instead of
// 16-way bank conflict), XCD-swizzled block index for qkv L2 locality.
// ---------------------------------------------------------------------------
__global__ __launch_bounds__(256)
void attn_tile(const bf16* __restrict__ qkv, bf16* __restrict__ aout)
{
    __shared__ __align__(16) bf16 Vt[4][64][40];
    __shared__ __align__(16) bf16 Ps[4][16][40];

    const int w    = threadIdx.x >> 6;
    const int lane = threadIdx.x & 63;
    const int c    = lane & 15;
    const int q    = lane >> 4;
    int bid = blockIdx.x;
    bid = (bid & 7) * 96 + (bid >> 3);     // XCD swizzle, 768 = 8*96, bijective
    const int wid  = bid * 4 + w;          // 0..3071
    const int it   = wid & 127;
    const int bh   = wid >> 7;             // 0..23
    const int h    = bh % 12;
    const int b    = bh / 12;
    const int I0   = it * 16;
    const int bbase = b * 2048;
    const int j0   = I0 - 7;

    // ---- V staging: transposed into Vt[d][j], XOR-swizzled columns ----
    #pragma unroll
    for (int itr = 0; itr < 4; ++itr) {
        int idx = itr * 64 + lane;        // 0..255
        int row = idx >> 3;               // j: 0..31
        int dc  = (idx & 7) * 8;          // d block: 0,8,...,56
        int jc  = j0 + row; jc = jc < 0 ? 0 : (jc > 2047 ? 2047 : jc);
        const bf16* base = qkv + (size_t)(bbase + jc) * 2304 + 1536 + h * 64 + dc;
        bf16x8 vv = *(const bf16x8*)base;
        #pragma unroll
        for (int e = 0; e < 8; ++e) {
            int d    = dc + e;
            int col2 = (row * 2) ^ (((d >> 3) & 3) << 4);   // swizzled byte col
            *(bf16*)((char*)&Vt[w][d][0] + col2) = vv[e];
        }
    }

    // ---- Q fragments (direct) ----
    const bf16* qrow = qkv + (size_t)(bbase + I0 + c) * 2304 + h * 64;
    bf16x8 aq0 = *(const bf16x8*)(qrow + q * 8);
    bf16x8 aq1 = *(const bf16x8*)(qrow + 32 + q * 8);

    // ---- QK^T with K B-fragments loaded directly from global ----
    floatx4 st[2] = {};
    #pragma unroll
    for (int t = 0; t < 2; ++t) {
        int jr = j0 + t * 16 + c;
        jr = jr < 0 ? 0 : (jr > 2047 ? 2047 : jr);
        const bf16* krow = qkv + (size_t)(bbase + jr) * 2304 + 768 + h * 64;
        bf16x8 k0 = *(const bf16x8*)(krow + q * 8);
        bf16x8 k1 = *(const bf16x8*)(krow + 32 + q * 8);
        st[t] = __builtin_amdgcn_mfma_f32_16x16x32_bf16(aq0, k0, st[t], 0, 0, 0);
        st[t] = __builtin_amdgcn_mfma_f32_16x16x32_bf16(aq1, k1, st[t], 0, 0, 0);
    }

    float s[2][4];
    #pragma unroll
    for (int t = 0; t < 2; ++t)
        #pragma unroll
        for (int r = 0; r < 4; ++r) {
            int il = q * 4 + r;
            int jl = t * 16 + c;
            int ja = j0 + jl;
            bool valid = (jl >= il) && (jl <= il + 14) && (ja >= 0) && (ja < 2048);
            s[t][r] = valid ? st[t][r] * 0.125f : -1e30f;
        }

    float l[4], p[2][4];
    #pragma unroll
    for (int r = 0; r < 4; ++r) {
        float m2 = fmaxf(s[0][r], s[1][r]);
        #pragma unroll
        for (int mk = 1; mk < 16; mk <<= 1) m2 = fmaxf(m2, __shfl_xor(m2, mk, 64));
        p[0][r] = __expf(s[0][r] - m2);
        p[1][r] = __expf(s[1][r] - m2);
        float l2 = p[0][r] + p[1][r];
        #pragma unroll
        for (int mk = 1; mk < 16; mk <<= 1) l2 += __shfl_xor(l2, mk, 64);
        l[r] = l2;
    }

    // ---- P exchange (wave-private LDS, no block barrier needed) ----
    #pragma unroll
    for (int r = 0; r < 4; ++r) {
        Ps[w][q * 4 + r][c]      = (bf16)p[0][r];
        Ps[w][q * 4 + r][16 + c] = (bf16)p[1][r];
    }

    bf16x8 ap = *(const bf16x8*)(&Ps[w][c][q * 8]);
    floatx4 ov[4];
    #pragma unroll
    for (int nt = 0; nt < 4; ++nt) {
        int dr = nt * 16 + c;
        int cb = (q * 16) ^ (((dr >> 3) & 3) << 4);         // match write swizzle
        bf16x8 vf = *(const bf16x8*)((const char*)&Vt[w][dr][0] + cb);
        floatx4 z = {};
        ov[nt] = __builtin_amdgcn_mfma_f32_16x16x32_bf16(ap, vf, z, 0, 0, 0);
    }

    float rl[4];
    #pragma unroll
    for (int r = 0; r < 4; ++r) rl[r] = 1.0f / l[r];
    #pragma unroll
    for (int r = 0; r < 4; ++r) {
        bf16* orow = aout + (size_t)(bbase + I0 + q * 4 + r) * 768 + h * 64;
        #pragma unroll
        for (int nt = 0; nt < 4; ++nt)
            orow[nt * 16 + c] = (bf16)(ov[nt][r] * rl[r]);
    }
}

// ---------------------------------------------------------------------------
extern "C" void kernel_launch(void* const* d_in, const int* in_sizes, int n_in,
                              void* d_out, int out_size, void* d_ws, size_t ws_size,
                              hipStream_t stream)
{
    const float* x      = (const float*)d_in[0];  // [4096][768] f32
    const float* w_qkv  = (const float*)d_in[1];  // [2304][768] f32
    const float* w_proj = (const float*)d_in[2];  // [768][768]  f32
    const float* b_proj = (const float*)d_in[3];  // [768]       f32
    float* out = (float*)d_out;                   // [4096][768] f32

    bf16* qkv = (bf16*)d_ws;                      // [4096][2304] bf16, 18.87 MB
    const size_t QKV_B  = (size_t)4096 * 2304 * 2;
    const size_t AO_B   = (size_t)4096 * 768 * 2; // 6.29 MB
    const size_t XB_B   = (size_t)4096 * 768 * 2;
    const size_t WQKV_B = (size_t)2304 * 768 * 2;
    const size_t WPRJ_B = (size_t)768 * 768 * 2;

    if (ws_size >= QKV_B + AO_B + XB_B + WQKV_B + WPRJ_B) {
        // main path (R9 config + TM=64 GEMM2 + R11 swizzles + R12 BK=64)
        bf16* aout = (bf16*)((char*)d_ws + QKV_B);
        bf16* xb   = (bf16*)((char*)aout + AO_B);
        bf16* wqb  = (bf16*)((char*)xb + XB_B);
        bf16* wpb  = (bf16*)((char*)wqb + WQKV_B);

        const int n0 = 4096 * 768 / 4, n1 = 2304 * 768 / 4, n2 = 768 * 768 / 4;
        cvt3_f32_bf16<<<dim3((n0 + n1 + n2) / 256), 256, 0, stream>>>(
            x, w_qkv, w_proj, xb, wqb, wpb, n0, n1, n2);

        // 1) qkv = xb @ wqb^T   (TM=128, grid 576 blocks)
        gemm_bt<bf16, false, false, 128, 4096, 2304, 768, 768, 2304>
            <<<dim3(32, 18), 256, 0, stream>>>(xb, wqb, qkv, nullptr);

        // 2) attention -> dense [4096][768]
        attn_tile<<<dim3(768), 256, 0, stream>>>(qkv, aout);

        // 3) out = aout @ wpb^T + b_proj   (TM=64, grid 384 blocks)
        gemm_bt<float, false, false, 64, 4096, 768, 768, 768, 768>
            <<<dim3(64, 6), 256, 0, stream>>>(aout, wpb, out, b_proj);
    } else {
        // fallback: f32 cvt inside GEMM staging (R6-proven), minimal ws
        gemm_bt<bf16, true, true, 128, 4096, 2304, 768, 768, 2304>
            <<<dim3(32, 18), 256, 0, stream>>>(x, w_qkv, qkv, nullptr);

        bf16* aout = (bf16*)((char*)d_ws + QKV_B);
        attn_tile<<<dim3(768), 256, 0, stream>>>(qkv, aout);

        gemm_bt<float, false, true, 64, 4096, 768, 768, 768, 768>
            <<<dim3(64, 6), 256, 0, stream>>>(aout, w_proj, out, b_proj);
    }
}

// Round 4
// 123.506 us; speedup vs baseline: 1.0124x; 1.0124x over previous
//
#include <hip/hip_runtime.h>
#include <hip/hip_bf16.h>

typedef __bf16 bf16;
typedef bf16 bf16x4 __attribute__((ext_vector_type(4)));
typedef bf16 bf16x8 __attribute__((ext_vector_type(8)));
typedef float floatx4 __attribute__((ext_vector_type(4)));

#define GLOBAL_AS __attribute__((address_space(1)))
#define LDS_AS __attribute__((address_space(3)))

// compiler-fence + hardware barrier (no implicit vmcnt/lgkmcnt drain)
__device__ __forceinline__ void hard_barrier() {
    asm volatile("" ::: "memory");
    __builtin_amdgcn_s_barrier();
    asm volatile("" ::: "memory");
}

// ---------------------------------------------------------------------------
// f32 -> bf16 conversion for x, w_qkv, w_proj (float4 granular).
// ---------------------------------------------------------------------------
__global__ __launch_bounds__(256)
void cvt3_f32_bf16(const float* __restrict__ s0, const float* __restrict__ s1,
                   const float* __restrict__ s2, bf16* __restrict__ d0,
                   bf16* __restrict__ d1, bf16* __restrict__ d2,
                   int n0, int n1, int n2)
{
    int t = blockIdx.x * blockDim.x + threadIdx.x;
    const float* s; bf16* d; int i;
    if (t < n0)                { s = s0; d = d0; i = t; }
    else if (t < n0 + n1)      { s = s1; d = d1; i = t - n0; }
    else if (t < n0 + n1 + n2) { s = s2; d = d2; i = t - n0 - n1; }
    else return;
    float4 v = ((const float4*)s)[i];
    bf16x4 o = { (bf16)v.x, (bf16)v.y, (bf16)v.z, (bf16)v.w };
    ((bf16x4*)d)[i] = o;
}

// ---------------------------------------------------------------------------
// R14 (= R13 hardened): 256x256 phase-split GEMM (T2+T3+T4+T5) for qkv proj.
// C[m][n] = sum_k A[m][k] * W[n][k], A/W bf16 row-major, BK=64, 512 thr.
// - dbuf LDS 128KB, 1 block/CU, 8 waves (2Mx4N), wave tile 128x64.
// - counted vmcnt(8): tile t+1's 8 loads stay in flight across barriers.
// - 4 phases/tile {ds_read || 16 MFMA || setprio || barrier}, frag-reuse
//   order (B0,B1,B1,B0): 24 ds_read_b128 per tile.
// - T2 per rule #21: global_load_lds writes linearly -> k-slot XOR
//   (slot ^ row&7) applied to per-lane GLOBAL source addr and ds_read addr.
//   Row term drops out of bank index (128B stride); swizzle makes the
//   quarter-wave b128 read hit 8 distinct 16B slots -> 2-way (free).
// ---------------------------------------------------------------------------
template<typename CT, int M, int N, int K, int LDA, int LDC>
__global__ __launch_bounds__(512, 2)
void gemm8p_bt(const bf16* __restrict__ A, const bf16* __restrict__ W,
               CT* __restrict__ C)
{
    constexpr int NT = K / 64;                         // K-tiles
    __shared__ __align__(16) bf16 lds[2][2][256 * 64]; // [buf][A|W], 128 KiB

    const int tid  = threadIdx.x;
    const int lane = tid & 63;
    const int wave = tid >> 6;

    // XCD-chunked swizzle over 1-D grid (gridDim.x % 8 == 0 -> bijective)
    int lin = blockIdx.x;
    const int chx = gridDim.x >> 3;
    lin = (lin & 7) * chx + (lin >> 3);
    const int bx = lin / (N / 256);
    const int by = lin % (N / 256);
    const int row0 = bx * 256;
    const int col0 = by * 256;

    const int wm = (wave & 1) * 128;   // 2 M-waves
    const int wn = (wave >> 1) * 64;   // 4 N-waves

    const int fr  = lane & 15;
    const int fks = lane >> 4;         // 16B k-slot 0..3 within a 32-k half
    const int fr7 = fr & 7;

    // staging mapping: thread -> (row, 16B slot); swizzled global k-slot
    const int rl = tid >> 3;           // row within 64-row round
    const int sl = tid & 7;
    const int ss = sl ^ (rl & 7);      // T2: pre-swizzled global source slot

    floatx4 acc[8][4] = {};

    // stage one 256x64 operand tile: 4 rounds x (512 thr x 16B)
    auto stage = [&](const bf16* G, int ldg, int g0, int k0, bf16* Ld) {
        #pragma unroll
        for (int c = 0; c < 4; ++c) {
            const bf16* src = G + (size_t)(g0 + c * 64 + rl) * ldg + k0 + ss * 8;
            __builtin_amdgcn_global_load_lds((const GLOBAL_AS void*)src,
                (LDS_AS void*)(Ld + c * 4096 + wave * 512), 16, 0, 0);
        }
    };

    bf16x8 afA[4][2], bf0[2][2], bf1[2][2];

    auto loadA = [&](const bf16* Ab, int qi) {
        #pragma unroll
        for (int ii = 0; ii < 4; ++ii)
            #pragma unroll
            for (int kk = 0; kk < 2; ++kk)
                afA[ii][kk] = *(const bf16x8*)(Ab
                    + (wm + (qi + ii) * 16 + fr) * 64
                    + (((kk * 4 + fks) ^ fr7) * 8));
    };
    auto loadB = [&](const bf16* Bb, int qj, bf16x8 (&bb)[2][2]) {
        #pragma unroll
        for (int jj = 0; jj < 2; ++jj)
            #pragma unroll
            for (int kk = 0; kk < 2; ++kk)
                bb[jj][kk] = *(const bf16x8*)(Bb
                    + (wn + (qj + jj) * 16 + fr) * 64
                    + (((kk * 4 + fks) ^ fr7) * 8));
    };
    auto mfmaQ = [&](int qi, int qj, bf16x8 (&bb)[2][2]) {
        __builtin_amdgcn_s_setprio(1);
        #pragma unroll
        for (int ii = 0; ii < 4; ++ii)
            #pragma unroll
            for (int jj = 0; jj < 2; ++jj)
                #pragma unroll
                for (int kk = 0; kk < 2; ++kk)
                    acc[qi + ii][qj + jj] =
                        __builtin_amdgcn_mfma_f32_16x16x32_bf16(
                            afA[ii][kk], bb[jj][kk], acc[qi + ii][qj + jj],
                            0, 0, 0);
        __builtin_amdgcn_s_setprio(0);
        hard_barrier();
    };

    // prologue: stage tile 0 into buf 0
    stage(A, LDA, row0, 0, lds[0][0]);
    stage(W, K,   col0, 0, lds[0][1]);

    for (int t = 0; t < NT; ++t) {
        const int buf = t & 1;
        const bf16* Ab = lds[buf][0];
        const bf16* Bb = lds[buf][1];
        // stage next tile into the buffer freed by tile t-1's last barrier,
        // then counted-wait for THIS tile's 8 loads (the oldest 8).
        if (t + 1 < NT) {
            stage(A, LDA, row0, (t + 1) * 64, lds[buf ^ 1][0]);
            stage(W, K,   col0, (t + 1) * 64, lds[buf ^ 1][1]);
            asm volatile("s_waitcnt vmcnt(8)" ::: "memory");
        } else {
            asm volatile("s_waitcnt vmcnt(0)" ::: "memory");
        }
        hard_barrier();

        loadA(Ab, 0);
        loadB(Bb, 0, bf0);
        loadB(Bb, 2, bf1);
        mfmaQ(0, 0, bf0);   // phase 0: rows 0-3, cols 0-1
        mfmaQ(0, 2, bf1);   // phase 1: rows 0-3, cols 2-3 (A reused)
        loadA(Ab, 4);
        mfmaQ(4, 2, bf1);   // phase 2: rows 4-7, cols 2-3 (B1 reused)
        mfmaQ(4, 0, bf0);   // phase 3: rows 4-7, cols 0-1 (B0 reused)
    }

    const int fc  = lane & 15;
    const int fr4 = (lane >> 4) * 4;
    #pragma unroll
    for (int i = 0; i < 8; ++i)
        #pragma unroll
        for (int j = 0; j < 4; ++j) {
            const int col = col0 + wn + j * 16 + fc;
            #pragma unroll
            for (int r = 0; r < 4; ++r) {
                const int row = row0 + wm + i * 16 + fr4 + r;
                C[(size_t)row * LDC + col] = (CT)acc[i][j][r];
            }
        }
}

// ---------------------------------------------------------------------------
// R11 GEMM (BK=32, verified 121.9us config): used for GEMM2 and fallback.
// ---------------------------------------------------------------------------
template<typename CT, bool AF32, bool WF32, int TM, int M, int N, int K,
         int LDA, int LDC>
__global__ __launch_bounds__(256, 2)
void gemm_bt(const void* __restrict__ Av, const void* __restrict__ Wv,
             CT* __restrict__ C, const float* __restrict__ bias)
{
    constexpr int MI = TM / 32;          // acc rows per wave (4 or 2)
    __shared__ __align__(16) bf16 As[TM * 32];
    __shared__ __align__(16) bf16 Bs[128 * 32];

    const int tid  = threadIdx.x;
    const int lane = tid & 63;
    const int wave = tid >> 6;

    // XCD swizzle (T1)
    const int lin = blockIdx.y * gridDim.x + blockIdx.x;
    const int ch  = gridDim.x >> 3;
    const int xcd = lin & 7;
    const int rr  = lin >> 3;
    const int bx  = xcd * ch + (rr % ch);
    const int by  = rr / ch;

    const int row0 = bx * TM;
    const int col0 = by * 128;

    const int wm = (wave & 1) * (TM / 2);
    const int wn = (wave >> 1) * 64;

    floatx4 acc[MI][4] = {};

    const int fr = lane & 15;
    const int fk = (lane >> 4) * 8;

    const int lr = lane >> 2;        // async staging: row within 16-row chunk
    const int lk = (lane & 3) * 8;   //                k offset within row

    for (int k0 = 0; k0 < K; k0 += 32) {
        // ---- A staging ----
        if (AF32) {
            constexpr int NV = TM * 4;             // # of 8-elem vectors
            #pragma unroll
            for (int c = 0; c < NV / 256; ++c) {
                const int idx = tid + c * 256;
                const int r   = idx >> 2;
                const int cb  = (idx & 3) * 8;
                const float4* g = (const float4*)((const float*)Av
                                   + (size_t)(row0 + r) * LDA + k0 + cb);
                float4 g0 = g[0], g1 = g[1];
                bf16x8 va;
                va[0]=(bf16)g0.x; va[1]=(bf16)g0.y; va[2]=(bf16)g0.z; va[3]=(bf16)g0.w;
                va[4]=(bf16)g1.x; va[5]=(bf16)g1.y; va[6]=(bf16)g1.z; va[7]=(bf16)g1.w;
                *(bf16x8*)(As + r * 32 + cb) = va;
            }
        } else {
            constexpr int CAW = TM / 64;           // A chunks per wave
            #pragma unroll
            for (int c = 0; c < CAW; ++c) {
                const int chunk = wave * CAW + c;
                const int r = chunk * 16 + lr;
                const bf16* gA = (const bf16*)Av + (size_t)(row0 + r) * LDA + k0 + lk;
                __builtin_amdgcn_global_load_lds((const GLOBAL_AS void*)gA,
                                                 (LDS_AS void*)(As + chunk * 512),
                                                 16, 0, 0);
            }
        }
        // ---- W staging (always 128x32 tile = 8 chunks, 2 per wave) ----
        if (WF32) {
            #pragma unroll
            for (int c = 0; c < 2; ++c) {
                const int idx = tid + c * 256;
                const int r   = idx >> 2;
                const int cb  = (idx & 3) * 8;
                const float4* g = (const float4*)((const float*)Wv
                                   + (size_t)(col0 + r) * K + k0 + cb);
                float4 g0 = g[0], g1 = g[1];
                bf16x8 vw;
                vw[0]=(bf16)g0.x; vw[1]=(bf16)g0.y; vw[2]=(bf16)g0.z; vw[3]=(bf16)g0.w;
                vw[4]=(bf16)g1.x; vw[5]=(bf16)g1.y; vw[6]=(bf16)g1.z; vw[7]=(bf16)g1.w;
                *(bf16x8*)(Bs + r * 32 + cb) = vw;
            }
        } else {
            #pragma unroll
            for (int c = 0; c < 2; ++c) {
                const int chunk = wave * 2 + c;
                const int r = chunk * 16 + lr;
                const bf16* gB = (const bf16*)Wv + (size_t)(col0 + r) * K + k0 + lk;
                __builtin_amdgcn_global_load_lds((const GLOBAL_AS void*)gB,
                                                 (LDS_AS void*)(Bs + chunk * 512),
                                                 16, 0, 0);
            }
        }
        __syncthreads();

        bf16x8 af[MI], bfr[4];
        #pragma unroll
        for (int i = 0; i < MI; ++i)
            af[i]  = *(const bf16x8*)(As + (wm + i * 16 + fr) * 32 + fk);
        #pragma unroll
        for (int j = 0; j < 4; ++j)
            bfr[j] = *(const bf16x8*)(Bs + (wn + j * 16 + fr) * 32 + fk);
        #pragma unroll
        for (int i = 0; i < MI; ++i)
            #pragma unroll
            for (int j = 0; j < 4; ++j)
                acc[i][j] = __builtin_amdgcn_mfma_f32_16x16x32_bf16(
                    af[i], bfr[j], acc[i][j], 0, 0, 0);

        __syncthreads();
    }

    const int fc  = lane & 15;
    const int fr4 = (lane >> 4) * 4;
    #pragma unroll
    for (int i = 0; i < MI; ++i) {
        #pragma unroll
        for (int j = 0; j < 4; ++j) {
            const int col = col0 + wn + j * 16 + fc;
            const float b = bias ? bias[col] : 0.0f;
            #pragma unroll
            for (int r = 0; r < 4; ++r) {
                const int row = row0 + wm + i * 16 + fr4 + r;
                C[(size_t)row * LDC + col] = (CT)(acc[i][j][r] + b);
            }
        }
    }
}

// ---------------------------------------------------------------------------
// MFMA local-window attention (R11 verified). One wave per (b,h,16-row tile).
// Wave-private LDS (no block barriers), direct-K fragments, XOR-swizzled Vt,
// XCD-swizzled block index.
// ---------------------------------------------------------------------------
__global__ __launch_bounds__(256)
void attn_tile(const bf16* __restrict__ qkv, bf16* __restrict__ aout)
{
    __shared__ __align__(16) bf16 Vt[4][64][40];
    __shared__ __align__(16) bf16 Ps[4][16][40];

    const int w    = threadIdx.x >> 6;
    const int lane = threadIdx.x & 63;
    const int c    = lane & 15;
    const int q    = lane >> 4;
    int bid = blockIdx.x;
    bid = (bid & 7) * 96 + (bid >> 3);     // XCD swizzle, 768 = 8*96, bijective
    const int wid  = bid * 4 + w;          // 0..3071
    const int it   = wid & 127;
    const int bh   = wid >> 7;             // 0..23
    const int h    = bh % 12;
    const int b    = bh / 12;
    const int I0   = it * 16;
    const int bbase = b * 2048;
    const int j0   = I0 - 7;

    // ---- V staging: transposed into Vt[d][j], XOR-swizzled columns ----
    #pragma unroll
    for (int itr = 0; itr < 4; ++itr) {
        int idx = itr * 64 + lane;        // 0..255
        int row = idx >> 3;               // j: 0..31
        int dc  = (idx & 7) * 8;          // d block: 0,8,...,56
        int jc  = j0 + row; jc = jc < 0 ? 0 : (jc > 2047 ? 2047 : jc);
        const bf16* base = qkv + (size_t)(bbase + jc) * 2304 + 1536 + h * 64 + dc;
        bf16x8 vv = *(const bf16x8*)base;
        #pragma unroll
        for (int e = 0; e < 8; ++e) {
            int d    = dc + e;
            int col2 = (row * 2) ^ (((d >> 3) & 3) << 4);   // swizzled byte col
            *(bf16*)((char*)&Vt[w][d][0] + col2) = vv[e];
        }
    }

    // ---- Q fragments (direct) ----
    const bf16* qrow = qkv + (size_t)(bbase + I0 + c) * 2304 + h * 64;
    bf16x8 aq0 = *(const bf16x8*)(qrow + q * 8);
    bf16x8 aq1 = *(const bf16x8*)(qrow + 32 + q * 8);

    // ---- QK^T with K B-fragments loaded directly from global ----
    floatx4 st[2] = {};
    #pragma unroll
    for (int t = 0; t < 2; ++t) {
        int jr = j0 + t * 16 + c;
        jr = jr < 0 ? 0 : (jr > 2047 ? 2047 : jr);
        const bf16* krow = qkv + (size_t)(bbase + jr) * 2304 + 768 + h * 64;
        bf16x8 k0 = *(const bf16x8*)(krow + q * 8);
        bf16x8 k1 = *(const bf16x8*)(krow + 32 + q * 8);
        st[t] = __builtin_amdgcn_mfma_f32_16x16x32_bf16(aq0, k0, st[t], 0, 0, 0);
        st[t] = __builtin_amdgcn_mfma_f32_16x16x32_bf16(aq1, k1, st[t], 0, 0, 0);
    }

    float s[2][4];
    #pragma unroll
    for (int t = 0; t < 2; ++t)
        #pragma unroll
        for (int r = 0; r < 4; ++r) {
            int il = q * 4 + r;
            int jl = t * 16 + c;
            int ja = j0 + jl;
            bool valid = (jl >= il) && (jl <= il + 14) && (ja >= 0) && (ja < 2048);
            s[t][r] = valid ? st[t][r] * 0.125f : -1e30f;
        }

    float l[4], p[2][4];
    #pragma unroll
    for (int r = 0; r < 4; ++r) {
        float m2 = fmaxf(s[0][r], s[1][r]);
        #pragma unroll
        for (int mk = 1; mk < 16; mk <<= 1) m2 = fmaxf(m2, __shfl_xor(m2, mk, 64));
        p[0][r] = __expf(s[0][r] - m2);
        p[1][r] = __expf(s[1][r] - m2);
        float l2 = p[0][r] + p[1][r];
        #pragma unroll
        for (int mk = 1; mk < 16; mk <<= 1) l2 += __shfl_xor(l2, mk, 64);
        l[r] = l2;
    }

    // ---- P exchange (wave-private LDS, no block barrier needed) ----
    #pragma unroll
    for (int r = 0; r < 4; ++r) {
        Ps[w][q * 4 + r][c]      = (bf16)p[0][r];
        Ps[w][q * 4 + r][16 + c] = (bf16)p[1][r];
    }

    bf16x8 ap = *(const bf16x8*)(&Ps[w][c][q * 8]);
    floatx4 ov[4];
    #pragma unroll
    for (int nt = 0; nt < 4; ++nt) {
        int dr = nt * 16 + c;
        int cb = (q * 16) ^ (((dr >> 3) & 3) << 4);         // match write swizzle
        bf16x8 vf = *(const bf16x8*)((const char*)&Vt[w][dr][0] + cb);
        floatx4 z = {};
        ov[nt] = __builtin_amdgcn_mfma_f32_16x16x32_bf16(ap, vf, z, 0, 0, 0);
    }

    float rl[4];
    #pragma unroll
    for (int r = 0; r < 4; ++r) rl[r] = 1.0f / l[r];
    #pragma unroll
    for (int r = 0; r < 4; ++r) {
        bf16* orow = aout + (size_t)(bbase + I0 + q * 4 + r) * 768 + h * 64;
        #pragma unroll
        for (int nt = 0; nt < 4; ++nt)
            orow[nt * 16 + c] = (bf16)(ov[nt][r] * rl[r]);
    }
}

// ---------------------------------------------------------------------------
extern "C" void kernel_launch(void* const* d_in, const int* in_sizes, int n_in,
                              void* d_out, int out_size, void* d_ws, size_t ws_size,
                              hipStream_t stream)
{
    const float* x      = (const float*)d_in[0];  // [4096][768] f32
    const float* w_qkv  = (const float*)d_in[1];  // [2304][768] f32
    const float* w_proj = (const float*)d_in[2];  // [768][768]  f32
    const float* b_proj = (const float*)d_in[3];  // [768]       f32
    float* out = (float*)d_out;                   // [4096][768] f32

    bf16* qkv = (bf16*)d_ws;                      // [4096][2304] bf16, 18.87 MB
    const size_t QKV_B  = (size_t)4096 * 2304 * 2;
    const size_t AO_B   = (size_t)4096 * 768 * 2; // 6.29 MB
    const size_t XB_B   = (size_t)4096 * 768 * 2;
    const size_t WQKV_B = (size_t)2304 * 768 * 2;
    const size_t WPRJ_B = (size_t)768 * 768 * 2;

    if (ws_size >= QKV_B + AO_B + XB_B + WQKV_B + WPRJ_B) {
        // main path: cvt3 + phase-split GEMM1 + attn + R11 GEMM2
        bf16* aout = (bf16*)((char*)d_ws + QKV_B);
        bf16* xb   = (bf16*)((char*)aout + AO_B);
        bf16* wqb  = (bf16*)((char*)xb + XB_B);
        bf16* wpb  = (bf16*)((char*)wqb + WQKV_B);

        const int n0 = 4096 * 768 / 4, n1 = 2304 * 768 / 4, n2 = 768 * 768 / 4;
        cvt3_f32_bf16<<<dim3((n0 + n1 + n2) / 256), 256, 0, stream>>>(
            x, w_qkv, w_proj, xb, wqb, wpb, n0, n1, n2);

        // 1) qkv = xb @ wqb^T   (256x256 phase-split, 144 blocks x 512 thr)
        gemm8p_bt<bf16, 4096, 2304, 768, 768, 2304>
            <<<dim3(144), 512, 0, stream>>>(xb, wqb, qkv);

        // 2) attention -> dense [4096][768]
        attn_tile<<<dim3(768), 256, 0, stream>>>(qkv, aout);

        // 3) out = aout @ wpb^T + b_proj   (TM=64, BK=32, grid 384 blocks)
        gemm_bt<float, false, false, 64, 4096, 768, 768, 768, 768>
            <<<dim3(64, 6), 256, 0, stream>>>(aout, wpb, out, b_proj);
    } else {
        // fallback: f32 cvt inside GEMM staging (R6-proven), minimal ws
        gemm_bt<bf16, true, true, 128, 4096, 2304, 768, 768, 2304>
            <<<dim3(32, 18), 256, 0, stream>>>(x, w_qkv, qkv, nullptr);

        bf16* aout = (bf16*)((char*)d_ws + QKV_B);
        attn_tile<<<dim3(768), 256, 0, stream>>>(qkv, aout);

        gemm_bt<float, false, true, 64, 4096, 768, 768, 768, 768>
            <<<dim3(64, 6), 256, 0, stream>>>(aout, w_proj, out, b_proj);
    }
}

// Round 5
// 118.706 us; speedup vs baseline: 1.0533x; 1.0404x over previous
//
#include <hip/hip_runtime.h>
#include <hip/hip_bf16.h>

typedef __bf16 bf16;
typedef bf16 bf16x4 __attribute__((ext_vector_type(4)));
typedef bf16 bf16x8 __attribute__((ext_vector_type(8)));
typedef float floatx4 __attribute__((ext_vector_type(4)));

#define GLOBAL_AS __attribute__((address_space(1)))
#define LDS_AS __attribute__((address_space(3)))

// compiler-fence + hardware barrier (no implicit vmcnt/lgkmcnt drain)
__device__ __forceinline__ void hard_barrier() {
    asm volatile("" ::: "memory");
    __builtin_amdgcn_s_barrier();
    asm volatile("" ::: "memory");
}

// ---------------------------------------------------------------------------
// f32 -> bf16 conversion for x, w_qkv, w_proj (float4 granular).
// ---------------------------------------------------------------------------
__global__ __launch_bounds__(256)
void cvt3_f32_bf16(const float* __restrict__ s0, const float* __restrict__ s1,
                   const float* __restrict__ s2, bf16* __restrict__ d0,
                   bf16* __restrict__ d1, bf16* __restrict__ d2,
                   int n0, int n1, int n2)
{
    int t = blockIdx.x * blockDim.x + threadIdx.x;
    const float* s; bf16* d; int i;
    if (t < n0)                { s = s0; d = d0; i = t; }
    else if (t < n0 + n1)      { s = s1; d = d1; i = t - n0; }
    else if (t < n0 + n1 + n2) { s = s2; d = d2; i = t - n0 - n1; }
    else return;
    float4 v = ((const float4*)s)[i];
    bf16x4 o = { (bf16)v.x, (bf16)v.y, (bf16)v.z, (bf16)v.w };
    ((bf16x4*)d)[i] = o;
}

// ---------------------------------------------------------------------------
// R15 GEMM1: 256x192 phase-split (T2+T3+T4+T5), grid 16x12 = 192 blocks ->
// single round on 256 CUs (R14's 144x256^2 grid was 56% CU-util; makespan
// here is 0.75x of it). BK=64, 512 thr, 8 waves 2Mx4N, wave tile 128x48,
// acc 8x3. LDS dbuf (32+24)KB x2 = 112 KB, 1 block/CU.
// - counted vmcnt(7): next tile's 7 loads/wave stay in flight across
//   barriers; never drained to 0 in steady state.
// - explicit lgkmcnt(0) before the closing barrier of each tile: ds_reads
//   provably complete before the next stage overwrites that buffer.
// - T2 per rule #21: k-slot XOR (slot ^ row&7) on the per-lane GLOBAL source
//   address (linear LDS dest) and on the ds_read address.
// ---------------------------------------------------------------------------
template<typename CT, int M, int N, int K, int LDA, int LDC>
__global__ __launch_bounds__(512, 2)
void gemm8p_bt(const bf16* __restrict__ A, const bf16* __restrict__ W,
               CT* __restrict__ C)
{
    constexpr int NT = K / 64;                          // K-tiles
    __shared__ __align__(16) bf16 lds[2][(256 + 192) * 64]; // 112 KiB

    const int tid  = threadIdx.x;
    const int lane = tid & 63;
    const int wave = tid >> 6;

    // XCD-chunked swizzle over 1-D grid (gridDim.x % 8 == 0 -> bijective)
    int lin = blockIdx.x;
    const int chx = gridDim.x >> 3;
    lin = (lin & 7) * chx + (lin >> 3);
    const int bx = lin / (N / 192);
    const int by = lin % (N / 192);
    const int row0 = bx * 256;
    const int col0 = by * 192;

    const int wm = (wave & 1) * 128;   // 2 M-waves
    const int wn = (wave >> 1) * 48;   // 4 N-waves

    const int fr  = lane & 15;
    const int fks = lane >> 4;         // 16B k-slot 0..3 within a 32-k half
    const int fr7 = fr & 7;

    // staging mapping: thread -> (row, 16B slot); swizzled global k-slot
    const int rl = tid >> 3;           // row within 64-row round
    const int sl = tid & 7;
    const int ss = sl ^ (rl & 7);      // T2: pre-swizzled global source slot

    floatx4 acc[8][3] = {};

    // stage A: 256x64 tile (4 rounds), B: 192x64 tile (3 rounds)
    auto stageA = [&](int k0, bf16* Ld) {
        #pragma unroll
        for (int c = 0; c < 4; ++c) {
            const bf16* src = A + (size_t)(row0 + c * 64 + rl) * LDA + k0 + ss * 8;
            __builtin_amdgcn_global_load_lds((const GLOBAL_AS void*)src,
                (LDS_AS void*)(Ld + c * 4096 + wave * 512), 16, 0, 0);
        }
    };
    auto stageB = [&](int k0, bf16* Ld) {
        #pragma unroll
        for (int c = 0; c < 3; ++c) {
            const bf16* src = W + (size_t)(col0 + c * 64 + rl) * K + k0 + ss * 8;
            __builtin_amdgcn_global_load_lds((const GLOBAL_AS void*)src,
                (LDS_AS void*)(Ld + c * 4096 + wave * 512), 16, 0, 0);
        }
    };

    bf16x8 afA[4][2], b01[2][2], b2[1][2];

    auto loadA = [&](const bf16* Ab, int qi) {
        #pragma unroll
        for (int ii = 0; ii < 4; ++ii)
            #pragma unroll
            for (int kk = 0; kk < 2; ++kk)
                afA[ii][kk] = *(const bf16x8*)(Ab
                    + (wm + (qi + ii) * 16 + fr) * 64
                    + (((kk * 4 + fks) ^ fr7) * 8));
    };
    auto loadB01 = [&](const bf16* Bb) {
        #pragma unroll
        for (int jj = 0; jj < 2; ++jj)
            #pragma unroll
            for (int kk = 0; kk < 2; ++kk)
                b01[jj][kk] = *(const bf16x8*)(Bb
                    + (wn + jj * 16 + fr) * 64
                    + (((kk * 4 + fks) ^ fr7) * 8));
    };
    auto loadB2 = [&](const bf16* Bb) {
        #pragma unroll
        for (int kk = 0; kk < 2; ++kk)
            b2[0][kk] = *(const bf16x8*)(Bb
                + (wn + 2 * 16 + fr) * 64
                + (((kk * 4 + fks) ^ fr7) * 8));
    };
    auto mfma16 = [&](int qi) {        // qi rows x cols {0,1}
        __builtin_amdgcn_s_setprio(1);
        #pragma unroll
        for (int ii = 0; ii < 4; ++ii)
            #pragma unroll
            for (int jj = 0; jj < 2; ++jj)
                #pragma unroll
                for (int kk = 0; kk < 2; ++kk)
                    acc[qi + ii][jj] = __builtin_amdgcn_mfma_f32_16x16x32_bf16(
                        afA[ii][kk], b01[jj][kk], acc[qi + ii][jj], 0, 0, 0);
        __builtin_amdgcn_s_setprio(0);
        hard_barrier();
    };
    auto mfma8 = [&](int qi) {         // qi rows x col {2}
        __builtin_amdgcn_s_setprio(1);
        #pragma unroll
        for (int ii = 0; ii < 4; ++ii)
            #pragma unroll
            for (int kk = 0; kk < 2; ++kk)
                acc[qi + ii][2] = __builtin_amdgcn_mfma_f32_16x16x32_bf16(
                    afA[ii][kk], b2[0][kk], acc[qi + ii][2], 0, 0, 0);
        __builtin_amdgcn_s_setprio(0);
        hard_barrier();
    };

    // prologue: stage tile 0 into buf 0 (7 loads/wave outstanding)
    stageA(0, lds[0]);
    stageB(0, lds[0] + 256 * 64);

    for (int t = 0; t < NT; ++t) {
        const int buf = t & 1;
        const bf16* Ab = lds[buf];
        const bf16* Bb = lds[buf] + 256 * 64;
        // all ds_reads of the buffer we are about to overwrite are complete
        asm volatile("s_waitcnt lgkmcnt(0)" ::: "memory");
        if (t + 1 < NT) {
            stageA((t + 1) * 64, lds[buf ^ 1]);
            stageB((t + 1) * 64, lds[buf ^ 1] + 256 * 64);
            asm volatile("s_waitcnt vmcnt(7)" ::: "memory"); // tile t's 7 done
        } else {
            asm volatile("s_waitcnt vmcnt(0)" ::: "memory");
        }
        hard_barrier();

        loadA(Ab, 0);
        loadB01(Bb);
        loadB2(Bb);
        mfma16(0);          // phase 0: rows 0-3 x cols 0-1
        mfma8(0);           // phase 1: rows 0-3 x col 2   (A reused)
        loadA(Ab, 4);
        mfma8(4);           // phase 2: rows 4-7 x col 2   (B2 reused)
        mfma16(4);          // phase 3: rows 4-7 x cols 0-1 (B01 reused)
    }

    const int fc  = lane & 15;
    const int fr4 = (lane >> 4) * 4;
    #pragma unroll
    for (int i = 0; i < 8; ++i)
        #pragma unroll
        for (int j = 0; j < 3; ++j) {
            const int col = col0 + wn + j * 16 + fc;
            #pragma unroll
            for (int r = 0; r < 4; ++r) {
                const int row = row0 + wm + i * 16 + fr4 + r;
                C[(size_t)row * LDC + col] = (CT)acc[i][j][r];
            }
        }
}

// ---------------------------------------------------------------------------
// R15 GEMM2: pipelined gemm_bt (TM x 128, BK=32, bf16 operands only).
// T3-minimum 2-phase with COUNTED vmcnt: stage tile t+1 (3 or 4 loads/wave)
// first, wait vmcnt(L) = exactly tile t's loads, keep t+1's in flight across
// both barriers. Explicit lgkmcnt(0) before the closing barrier guarantees
// ds_reads of a buffer complete before the stage that overwrites it.
// ---------------------------------------------------------------------------
template<typename CT, int TM, int M, int N, int K, int LDA, int LDC>
__global__ __launch_bounds__(256, 2)
void gemm_bt_p(const bf16* __restrict__ A, const bf16* __restrict__ W,
               CT* __restrict__ C, const float* __restrict__ bias)
{
    constexpr int MI  = TM / 32;         // acc rows per wave (4 or 2)
    constexpr int CAW = TM / 64;         // A chunks per wave (2 or 1)
    constexpr int NT  = K / 32;
    __shared__ __align__(16) bf16 As[2][TM * 32];
    __shared__ __align__(16) bf16 Bs[2][128 * 32];

    const int tid  = threadIdx.x;
    const int lane = tid & 63;
    const int wave = tid >> 6;

    // XCD swizzle (T1)
    const int lin = blockIdx.y * gridDim.x + blockIdx.x;
    const int ch  = gridDim.x >> 3;
    const int xcd = lin & 7;
    const int rr  = lin >> 3;
    const int bx  = xcd * ch + (rr % ch);
    const int by  = rr / ch;

    const int row0 = bx * TM;
    const int col0 = by * 128;

    const int wm = (wave & 1) * (TM / 2);
    const int wn = (wave >> 1) * 64;

    floatx4 acc[MI][4] = {};

    const int fr = lane & 15;
    const int fk = (lane >> 4) * 8;

    const int lr = lane >> 2;        // staging: row within 16-row chunk
    const int lk = (lane & 3) * 8;   //          k offset within row

    auto stage = [&](int k0, int buf) {
        #pragma unroll
        for (int c = 0; c < CAW; ++c) {
            const int chunk = wave * CAW + c;
            const int r = chunk * 16 + lr;
            const bf16* gA = A + (size_t)(row0 + r) * LDA + k0 + lk;
            __builtin_amdgcn_global_load_lds((const GLOBAL_AS void*)gA,
                                             (LDS_AS void*)(As[buf] + chunk * 512),
                                             16, 0, 0);
        }
        #pragma unroll
        for (int c = 0; c < 2; ++c) {
            const int chunk = wave * 2 + c;
            const int r = chunk * 16 + lr;
            const bf16* gB = W + (size_t)(col0 + r) * K + k0 + lk;
            __builtin_amdgcn_global_load_lds((const GLOBAL_AS void*)gB,
                                             (LDS_AS void*)(Bs[buf] + chunk * 512),
                                             16, 0, 0);
        }
    };

    stage(0, 0);
    for (int t = 0; t < NT; ++t) {
        const int buf = t & 1;
        if (t + 1 < NT) {
            stage((t + 1) * 32, buf ^ 1);
            if (TM == 64) asm volatile("s_waitcnt vmcnt(3)" ::: "memory");
            else          asm volatile("s_waitcnt vmcnt(4)" ::: "memory");
        } else {
            asm volatile("s_waitcnt vmcnt(0)" ::: "memory");
        }
        hard_barrier();

        bf16x8 af[MI], bfr[4];
        #pragma unroll
        for (int i = 0; i < MI; ++i)
            af[i]  = *(const bf16x8*)(As[buf] + (wm + i * 16 + fr) * 32 + fk);
        #pragma unroll
        for (int j = 0; j < 4; ++j)
            bfr[j] = *(const bf16x8*)(Bs[buf] + (wn + j * 16 + fr) * 32 + fk);
        #pragma unroll
        for (int i = 0; i < MI; ++i)
            #pragma unroll
            for (int j = 0; j < 4; ++j)
                acc[i][j] = __builtin_amdgcn_mfma_f32_16x16x32_bf16(
                    af[i], bfr[j], acc[i][j], 0, 0, 0);

        asm volatile("s_waitcnt lgkmcnt(0)" ::: "memory");
        hard_barrier();
    }

    const int fc  = lane & 15;
    const int fr4 = (lane >> 4) * 4;
    #pragma unroll
    for (int i = 0; i < MI; ++i) {
        #pragma unroll
        for (int j = 0; j < 4; ++j) {
            const int col = col0 + wn + j * 16 + fc;
            const float b = bias ? bias[col] : 0.0f;
            #pragma unroll
            for (int r = 0; r < 4; ++r) {
                const int row = row0 + wm + i * 16 + fr4 + r;
                C[(size_t)row * LDC + col] = (CT)(acc[i][j][r] + b);
            }
        }
    }
}

// ---------------------------------------------------------------------------
// R6-proven f32-capable GEMM (non-pipelined) — fallback path only.
// ---------------------------------------------------------------------------
template<typename CT, bool AF32, bool WF32, int TM, int M, int N, int K,
         int LDA, int LDC>
__global__ __launch_bounds__(256, 2)
void gemm_bt(const void* __restrict__ Av, const void* __restrict__ Wv,
             CT* __restrict__ C, const float* __restrict__ bias)
{
    constexpr int MI = TM / 32;
    __shared__ __align__(16) bf16 As[TM * 32];
    __shared__ __align__(16) bf16 Bs[128 * 32];

    const int tid  = threadIdx.x;
    const int lane = tid & 63;
    const int wave = tid >> 6;

    const int lin = blockIdx.y * gridDim.x + blockIdx.x;
    const int ch  = gridDim.x >> 3;
    const int xcd = lin & 7;
    const int rr  = lin >> 3;
    const int bx  = xcd * ch + (rr % ch);
    const int by  = rr / ch;

    const int row0 = bx * TM;
    const int col0 = by * 128;

    const int wm = (wave & 1) * (TM / 2);
    const int wn = (wave >> 1) * 64;

    floatx4 acc[MI][4] = {};

    const int fr = lane & 15;
    const int fk = (lane >> 4) * 8;

    const int lr = lane >> 2;
    const int lk = (lane & 3) * 8;

    for (int k0 = 0; k0 < K; k0 += 32) {
        if (AF32) {
            constexpr int NV = TM * 4;
            #pragma unroll
            for (int c = 0; c < NV / 256; ++c) {
                const int idx = tid + c * 256;
                const int r   = idx >> 2;
                const int cb  = (idx & 3) * 8;
                const float4* g = (const float4*)((const float*)Av
                                   + (size_t)(row0 + r) * LDA + k0 + cb);
                float4 g0 = g[0], g1 = g[1];
                bf16x8 va;
                va[0]=(bf16)g0.x; va[1]=(bf16)g0.y; va[2]=(bf16)g0.z; va[3]=(bf16)g0.w;
                va[4]=(bf16)g1.x; va[5]=(bf16)g1.y; va[6]=(bf16)g1.z; va[7]=(bf16)g1.w;
                *(bf16x8*)(As + r * 32 + cb) = va;
            }
        } else {
            constexpr int CAW = TM / 64;
            #pragma unroll
            for (int c = 0; c < CAW; ++c) {
                const int chunk = wave * CAW + c;
                const int r = chunk * 16 + lr;
                const bf16* gA = (const bf16*)Av + (size_t)(row0 + r) * LDA + k0 + lk;
                __builtin_amdgcn_global_load_lds((const GLOBAL_AS void*)gA,
                                                 (LDS_AS void*)(As + chunk * 512),
                                                 16, 0, 0);
            }
        }
        if (WF32) {
            #pragma unroll
            for (int c = 0; c < 2; ++c) {
                const int idx = tid + c * 256;
                const int r   = idx >> 2;
                const int cb  = (idx & 3) * 8;
                const float4* g = (const float4*)((const float*)Wv
                                   + (size_t)(col0 + r) * K + k0 + cb);
                float4 g0 = g[0], g1 = g[1];
                bf16x8 vw;
                vw[0]=(bf16)g0.x; vw[1]=(bf16)g0.y; vw[2]=(bf16)g0.z; vw[3]=(bf16)g0.w;
                vw[4]=(bf16)g1.x; vw[5]=(bf16)g1.y; vw[6]=(bf16)g1.z; vw[7]=(bf16)g1.w;
                *(bf16x8*)(Bs + r * 32 + cb) = vw;
            }
        } else {
            #pragma unroll
            for (int c = 0; c < 2; ++c) {
                const int chunk = wave * 2 + c;
                const int r = chunk * 16 + lr;
                const bf16* gB = (const bf16*)Wv + (size_t)(col0 + r) * K + k0 + lk;
                __builtin_amdgcn_global_load_lds((const GLOBAL_AS void*)gB,
                                                 (LDS_AS void*)(Bs + chunk * 512),
                                                 16, 0, 0);
            }
        }
        __syncthreads();

        bf16x8 af[MI], bfr[4];
        #pragma unroll
        for (int i = 0; i < MI; ++i)
            af[i]  = *(const bf16x8*)(As + (wm + i * 16 + fr) * 32 + fk);
        #pragma unroll
        for (int j = 0; j < 4; ++j)
            bfr[j] = *(const bf16x8*)(Bs + (wn + j * 16 + fr) * 32 + fk);
        #pragma unroll
        for (int i = 0; i < MI; ++i)
            #pragma unroll
            for (int j = 0; j < 4; ++j)
                acc[i][j] = __builtin_amdgcn_mfma_f32_16x16x32_bf16(
                    af[i], bfr[j], acc[i][j], 0, 0, 0);

        __syncthreads();
    }

    const int fc  = lane & 15;
    const int fr4 = (lane >> 4) * 4;
    #pragma unroll
    for (int i = 0; i < MI; ++i) {
        #pragma unroll
        for (int j = 0; j < 4; ++j) {
            const int col = col0 + wn + j * 16 + fc;
            const float b = bias ? bias[col] : 0.0f;
            #pragma unroll
            for (int r = 0; r < 4; ++r) {
                const int row = row0 + wm + i * 16 + fr4 + r;
                C[(size_t)row * LDC + col] = (CT)(acc[i][j][r] + b);
            }
        }
    }
}

// ---------------------------------------------------------------------------
// MFMA local-window attention (R11 verified). One wave per (b,h,16-row tile).
// Wave-private LDS (no block barriers), direct-K fragments, XOR-swizzled Vt,
// XCD-swizzled block index.
// ---------------------------------------------------------------------------
__global__ __launch_bounds__(256)
void attn_tile(const bf16* __restrict__ qkv, bf16* __restrict__ aout)
{
    __shared__ __align__(16) bf16 Vt[4][64][40];
    __shared__ __align__(16) bf16 Ps[4][16][40];

    const int w    = threadIdx.x >> 6;
    const int lane = threadIdx.x & 63;
    const int c    = lane & 15;
    const int q    = lane >> 4;
    int bid = blockIdx.x;
    bid = (bid & 7) * 96 + (bid >> 3);     // XCD swizzle, 768 = 8*96, bijective
    const int wid  = bid * 4 + w;          // 0..3071
    const int it   = wid & 127;
    const int bh   = wid >> 7;             // 0..23
    const int h    = bh % 12;
    const int b    = bh / 12;
    const int I0   = it * 16;
    const int bbase = b * 2048;
    const int j0   = I0 - 7;

    // ---- V staging: transposed into Vt[d][j], XOR-swizzled columns ----
    #pragma unroll
    for (int itr = 0; itr < 4; ++itr) {
        int idx = itr * 64 + lane;        // 0..255
        int row = idx >> 3;               // j: 0..31
        int dc  = (idx & 7) * 8;          // d block: 0,8,...,56
        int jc  = j0 + row; jc = jc < 0 ? 0 : (jc > 2047 ? 2047 : jc);
        const bf16* base = qkv + (size_t)(bbase + jc) * 2304 + 1536 + h * 64 + dc;
        bf16x8 vv = *(const bf16x8*)base;
        #pragma unroll
        for (int e = 0; e < 8; ++e) {
            int d    = dc + e;
            int col2 = (row * 2) ^ (((d >> 3) & 3) << 4);   // swizzled byte col
            *(bf16*)((char*)&Vt[w][d][0] + col2) = vv[e];
        }
    }

    // ---- Q fragments (direct) ----
    const bf16* qrow = qkv + (size_t)(bbase + I0 + c) * 2304 + h * 64;
    bf16x8 aq0 = *(const bf16x8*)(qrow + q * 8);
    bf16x8 aq1 = *(const bf16x8*)(qrow + 32 + q * 8);

    // ---- QK^T with K B-fragments loaded directly from global ----
    floatx4 st[2] = {};
    #pragma unroll
    for (int t = 0; t < 2; ++t) {
        int jr = j0 + t * 16 + c;
        jr = jr < 0 ? 0 : (jr > 2047 ? 2047 : jr);
        const bf16* krow = qkv + (size_t)(bbase + jr) * 2304 + 768 + h * 64;
        bf16x8 k0 = *(const bf16x8*)(krow + q * 8);
        bf16x8 k1 = *(const bf16x8*)(krow + 32 + q * 8);
        st[t] = __builtin_amdgcn_mfma_f32_16x16x32_bf16(aq0, k0, st[t], 0, 0, 0);
        st[t] = __builtin_amdgcn_mfma_f32_16x16x32_bf16(aq1, k1, st[t], 0, 0, 0);
    }

    float s[2][4];
    #pragma unroll
    for (int t = 0; t < 2; ++t)
        #pragma unroll
        for (int r = 0; r < 4; ++r) {
            int il = q * 4 + r;
            int jl = t * 16 + c;
            int ja = j0 + jl;
            bool valid = (jl >= il) && (jl <= il + 14) && (ja >= 0) && (ja < 2048);
            s[t][r] = valid ? st[t][r] * 0.125f : -1e30f;
        }

    float l[4], p[2][4];
    #pragma unroll
    for (int r = 0; r < 4; ++r) {
        float m2 = fmaxf(s[0][r], s[1][r]);
        #pragma unroll
        for (int mk = 1; mk < 16; mk <<= 1) m2 = fmaxf(m2, __shfl_xor(m2, mk, 64));
        p[0][r] = __expf(s[0][r] - m2);
        p[1][r] = __expf(s[1][r] - m2);
        float l2 = p[0][r] + p[1][r];
        #pragma unroll
        for (int mk = 1; mk < 16; mk <<= 1) l2 += __shfl_xor(l2, mk, 64);
        l[r] = l2;
    }

    // ---- P exchange (wave-private LDS, no block barrier needed) ----
    #pragma unroll
    for (int r = 0; r < 4; ++r) {
        Ps[w][q * 4 + r][c]      = (bf16)p[0][r];
        Ps[w][q * 4 + r][16 + c] = (bf16)p[1][r];
    }

    bf16x8 ap = *(const bf16x8*)(&Ps[w][c][q * 8]);
    floatx4 ov[4];
    #pragma unroll
    for (int nt = 0; nt < 4; ++nt) {
        int dr = nt * 16 + c;
        int cb = (q * 16) ^ (((dr >> 3) & 3) << 4);         // match write swizzle
        bf16x8 vf = *(const bf16x8*)((const char*)&Vt[w][dr][0] + cb);
        floatx4 z = {};
        ov[nt] = __builtin_amdgcn_mfma_f32_16x16x32_bf16(ap, vf, z, 0, 0, 0);
    }

    float rl[4];
    #pragma unroll
    for (int r = 0; r < 4; ++r) rl[r] = 1.0f / l[r];
    #pragma unroll
    for (int r = 0; r < 4; ++r) {
        bf16* orow = aout + (size_t)(bbase + I0 + q * 4 + r) * 768 + h * 64;
        #pragma unroll
        for (int nt = 0; nt < 4; ++nt)
            orow[nt * 16 + c] = (bf16)(ov[nt][r] * rl[r]);
    }
}

// ---------------------------------------------------------------------------
extern "C" void kernel_launch(void* const* d_in, const int* in_sizes, int n_in,
                              void* d_out, int out_size, void* d_ws, size_t ws_size,
                              hipStream_t stream)
{
    const float* x      = (const float*)d_in[0];  // [4096][768] f32
    const float* w_qkv  = (const float*)d_in[1];  // [2304][768] f32
    const float* w_proj = (const float*)d_in[2];  // [768][768]  f32
    const float* b_proj = (const float*)d_in[3];  // [768]       f32
    float* out = (float*)d_out;                   // [4096][768] f32

    bf16* qkv = (bf16*)d_ws;                      // [4096][2304] bf16, 18.87 MB
    const size_t QKV_B  = (size_t)4096 * 2304 * 2;
    const size_t AO_B   = (size_t)4096 * 768 * 2; // 6.29 MB
    const size_t XB_B   = (size_t)4096 * 768 * 2;
    const size_t WQKV_B = (size_t)2304 * 768 * 2;
    const size_t WPRJ_B = (size_t)768 * 768 * 2;

    if (ws_size >= QKV_B + AO_B + XB_B + WQKV_B + WPRJ_B) {
        // main path: cvt3 + 256x192 phase-split GEMM1 + attn + pipelined GEMM2
        bf16* aout = (bf16*)((char*)d_ws + QKV_B);
        bf16* xb   = (bf16*)((char*)aout + AO_B);
        bf16* wqb  = (bf16*)((char*)xb + XB_B);
        bf16* wpb  = (bf16*)((char*)wqb + WQKV_B);

        const int n0 = 4096 * 768 / 4, n1 = 2304 * 768 / 4, n2 = 768 * 768 / 4;
        cvt3_f32_bf16<<<dim3((n0 + n1 + n2) / 256), 256, 0, stream>>>(
            x, w_qkv, w_proj, xb, wqb, wpb, n0, n1, n2);

        // 1) qkv = xb @ wqb^T   (256x192 phase-split, 192 blocks x 512 thr)
        gemm8p_bt<bf16, 4096, 2304, 768, 768, 2304>
            <<<dim3(192), 512, 0, stream>>>(xb, wqb, qkv);

        // 2) attention -> dense [4096][768]
        attn_tile<<<dim3(768), 256, 0, stream>>>(qkv, aout);

        // 3) out = aout @ wpb^T + b_proj (TM=64, BK=32, pipelined, 384 blocks)
        gemm_bt_p<float, 64, 4096, 768, 768, 768, 768>
            <<<dim3(64, 6), 256, 0, stream>>>(aout, wpb, out, b_proj);
    } else {
        // fallback: f32 cvt inside GEMM staging (R6-proven), minimal ws
        gemm_bt<bf16, true, true, 128, 4096, 2304, 768, 768, 2304>
            <<<dim3(32, 18), 256, 0, stream>>>(x, w_qkv, qkv, nullptr);

        bf16* aout = (bf16*)((char*)d_ws + QKV_B);
        attn_tile<<<dim3(768), 256, 0, stream>>>(qkv, aout);

        gemm_bt<float, false, true, 64, 4096, 768, 768, 768, 768>
            <<<dim3(64, 6), 256, 0, stream>>>(aout, w_proj, out, b_proj);
    }
}

// Round 7
// 115.355 us; speedup vs baseline: 1.0839x; 1.0290x over previous
//
#include <hip/hip_runtime.h>
#include <hip/hip_bf16.h>

typedef __bf16 bf16;
typedef bf16 bf16x4 __attribute__((ext_vector_type(4)));
typedef bf16 bf16x8 __attribute__((ext_vector_type(8)));
typedef float floatx4 __attribute__((ext_vector_type(4)));

#define GLOBAL_AS __attribute__((address_space(1)))
#define LDS_AS __attribute__((address_space(3)))

// compiler-fence + hardware barrier (no implicit vmcnt/lgkmcnt drain)
__device__ __forceinline__ void hard_barrier() {
    asm volatile("" ::: "memory");
    __builtin_amdgcn_s_barrier();
    asm volatile("" ::: "memory");
}

// ---------------------------------------------------------------------------
// f32 -> bf16 conversion for x, w_qkv, w_proj (float4 granular).
// ---------------------------------------------------------------------------
__global__ __launch_bounds__(256)
void cvt3_f32_bf16(const float* __restrict__ s0, const float* __restrict__ s1,
                   const float* __restrict__ s2, bf16* __restrict__ d0,
                   bf16* __restrict__ d1, bf16* __restrict__ d2,
                   int n0, int n1, int n2)
{
    int t = blockIdx.x * blockDim.x + threadIdx.x;
    const float* s; bf16* d; int i;
    if (t < n0)                { s = s0; d = d0; i = t; }
    else if (t < n0 + n1)      { s = s1; d = d1; i = t - n0; }
    else if (t < n0 + n1 + n2) { s = s2; d = d2; i = t - n0 - n1; }
    else return;
    float4 v = ((const float4*)s)[i];
    bf16x4 o = { (bf16)v.x, (bf16)v.y, (bf16)v.z, (bf16)v.w };
    ((bf16x4*)d)[i] = o;
}

// ---------------------------------------------------------------------------
// R15 GEMM1 (verified 118.7us): 256x192 phase-split (T2+T3+T4+T5),
// grid 16x12 = 192 blocks -> single round on 256 CUs. BK=64, 512 thr,
// 8 waves 2Mx4N, wave tile 128x48, acc 8x3. LDS dbuf 112 KB, 1 block/CU.
// counted vmcnt(7); lgkmcnt(0) before overwriting a buffer; T2 both-sides
// k-slot XOR (slot ^ row&7) on global source and ds_read.
// ---------------------------------------------------------------------------
template<typename CT, int M, int N, int K, int LDA, int LDC>
__global__ __launch_bounds__(512, 2)
void gemm8p_bt(const bf16* __restrict__ A, const bf16* __restrict__ W,
               CT* __restrict__ C)
{
    constexpr int NT = K / 64;                          // K-tiles
    __shared__ __align__(16) bf16 lds[2][(256 + 192) * 64]; // 112 KiB

    const int tid  = threadIdx.x;
    const int lane = tid & 63;
    const int wave = tid >> 6;

    // XCD-chunked swizzle over 1-D grid (gridDim.x % 8 == 0 -> bijective)
    int lin = blockIdx.x;
    const int chx = gridDim.x >> 3;
    lin = (lin & 7) * chx + (lin >> 3);
    const int bx = lin / (N / 192);
    const int by = lin % (N / 192);
    const int row0 = bx * 256;
    const int col0 = by * 192;

    const int wm = (wave & 1) * 128;   // 2 M-waves
    const int wn = (wave >> 1) * 48;   // 4 N-waves

    const int fr  = lane & 15;
    const int fks = lane >> 4;         // 16B k-slot 0..3 within a 32-k half
    const int fr7 = fr & 7;

    // staging mapping: thread -> (row, 16B slot); swizzled global k-slot
    const int rl = tid >> 3;           // row within 64-row round
    const int sl = tid & 7;
    const int ss = sl ^ (rl & 7);      // T2: pre-swizzled global source slot

    floatx4 acc[8][3] = {};

    // stage A: 256x64 tile (4 rounds), B: 192x64 tile (3 rounds)
    auto stageA = [&](int k0, bf16* Ld) {
        #pragma unroll
        for (int c = 0; c < 4; ++c) {
            const bf16* src = A + (size_t)(row0 + c * 64 + rl) * LDA + k0 + ss * 8;
            __builtin_amdgcn_global_load_lds((const GLOBAL_AS void*)src,
                (LDS_AS void*)(Ld + c * 4096 + wave * 512), 16, 0, 0);
        }
    };
    auto stageB = [&](int k0, bf16* Ld) {
        #pragma unroll
        for (int c = 0; c < 3; ++c) {
            const bf16* src = W + (size_t)(col0 + c * 64 + rl) * K + k0 + ss * 8;
            __builtin_amdgcn_global_load_lds((const GLOBAL_AS void*)src,
                (LDS_AS void*)(Ld + c * 4096 + wave * 512), 16, 0, 0);
        }
    };

    bf16x8 afA[4][2], b01[2][2], b2[1][2];

    auto loadA = [&](const bf16* Ab, int qi) {
        #pragma unroll
        for (int ii = 0; ii < 4; ++ii)
            #pragma unroll
            for (int kk = 0; kk < 2; ++kk)
                afA[ii][kk] = *(const bf16x8*)(Ab
                    + (wm + (qi + ii) * 16 + fr) * 64
                    + (((kk * 4 + fks) ^ fr7) * 8));
    };
    auto loadB01 = [&](const bf16* Bb) {
        #pragma unroll
        for (int jj = 0; jj < 2; ++jj)
            #pragma unroll
            for (int kk = 0; kk < 2; ++kk)
                b01[jj][kk] = *(const bf16x8*)(Bb
                    + (wn + jj * 16 + fr) * 64
                    + (((kk * 4 + fks) ^ fr7) * 8));
    };
    auto loadB2 = [&](const bf16* Bb) {
        #pragma unroll
        for (int kk = 0; kk < 2; ++kk)
            b2[0][kk] = *(const bf16x8*)(Bb
                + (wn + 2 * 16 + fr) * 64
                + (((kk * 4 + fks) ^ fr7) * 8));
    };
    auto mfma16 = [&](int qi) {        // qi rows x cols {0,1}
        __builtin_amdgcn_s_setprio(1);
        #pragma unroll
        for (int ii = 0; ii < 4; ++ii)
            #pragma unroll
            for (int jj = 0; jj < 2; ++jj)
                #pragma unroll
                for (int kk = 0; kk < 2; ++kk)
                    acc[qi + ii][jj] = __builtin_amdgcn_mfma_f32_16x16x32_bf16(
                        afA[ii][kk], b01[jj][kk], acc[qi + ii][jj], 0, 0, 0);
        __builtin_amdgcn_s_setprio(0);
        hard_barrier();
    };
    auto mfma8 = [&](int qi) {         // qi rows x col {2}
        __builtin_amdgcn_s_setprio(1);
        #pragma unroll
        for (int ii = 0; ii < 4; ++ii)
            #pragma unroll
            for (int kk = 0; kk < 2; ++kk)
                acc[qi + ii][2] = __builtin_amdgcn_mfma_f32_16x16x32_bf16(
                    afA[ii][kk], b2[0][kk], acc[qi + ii][2], 0, 0, 0);
        __builtin_amdgcn_s_setprio(0);
        hard_barrier();
    };

    // prologue: stage tile 0 into buf 0 (7 loads/wave outstanding)
    stageA(0, lds[0]);
    stageB(0, lds[0] + 256 * 64);

    for (int t = 0; t < NT; ++t) {
        const int buf = t & 1;
        const bf16* Ab = lds[buf];
        const bf16* Bb = lds[buf] + 256 * 64;
        // all ds_reads of the buffer we are about to overwrite are complete
        asm volatile("s_waitcnt lgkmcnt(0)" ::: "memory");
        if (t + 1 < NT) {
            stageA((t + 1) * 64, lds[buf ^ 1]);
            stageB((t + 1) * 64, lds[buf ^ 1] + 256 * 64);
            asm volatile("s_waitcnt vmcnt(7)" ::: "memory"); // tile t's 7 done
        } else {
            asm volatile("s_waitcnt vmcnt(0)" ::: "memory");
        }
        hard_barrier();

        loadA(Ab, 0);
        loadB01(Bb);
        loadB2(Bb);
        mfma16(0);          // phase 0: rows 0-3 x cols 0-1
        mfma8(0);           // phase 1: rows 0-3 x col 2   (A reused)
        loadA(Ab, 4);
        mfma8(4);           // phase 2: rows 4-7 x col 2   (B2 reused)
        mfma16(4);          // phase 3: rows 4-7 x cols 0-1 (B01 reused)
    }

    const int fc  = lane & 15;
    const int fr4 = (lane >> 4) * 4;
    #pragma unroll
    for (int i = 0; i < 8; ++i)
        #pragma unroll
        for (int j = 0; j < 3; ++j) {
            const int col = col0 + wn + j * 16 + fc;
            #pragma unroll
            for (int r = 0; r < 4; ++r) {
                const int row = row0 + wm + i * 16 + fr4 + r;
                C[(size_t)row * LDC + col] = (CT)acc[i][j][r];
            }
        }
}

// ---------------------------------------------------------------------------
// R16 GEMM2: 128x128 phase-split, grid 32x6 = 192 blocks -> single round.
// Same validated structure as GEMM1, scaled down: BK=64, 512 thr, 8 waves
// 2Mx4N, wave tile 64x32, acc 4x2. LDS dbuf 64 KB. Staged-bytes ratio
// (1/BM+1/BN) = 0.0156 vs old 64x128's 0.0234 (-33% L2 staging traffic).
// counted vmcnt(4) (A:2 + B:2 loads/wave/tile); lgkmcnt(0) before buffer
// overwrite; T2 both-sides swizzle; 2 phases x 16 MFMA with setprio.
// ---------------------------------------------------------------------------
template<typename CT, int M, int N, int K, int LDA, int LDC>
__global__ __launch_bounds__(512, 2)
void gemm8p2_bt(const bf16* __restrict__ A, const bf16* __restrict__ W,
                CT* __restrict__ C, const float* __restrict__ bias)
{
    constexpr int NT = K / 64;
    __shared__ __align__(16) bf16 lds[2][(128 + 128) * 64]; // 64 KiB

    const int tid  = threadIdx.x;
    const int lane = tid & 63;
    const int wave = tid >> 6;

    // XCD-chunked swizzle over 1-D grid (gridDim.x % 8 == 0 -> bijective)
    int lin = blockIdx.x;
    const int chx = gridDim.x >> 3;
    lin = (lin & 7) * chx + (lin >> 3);
    const int bx = lin / (N / 128);
    const int by = lin % (N / 128);
    const int row0 = bx * 128;
    const int col0 = by * 128;

    const int wm = (wave & 1) * 64;    // 2 M-waves
    const int wn = (wave >> 1) * 32;   // 4 N-waves

    const int fr  = lane & 15;
    const int fks = lane >> 4;
    const int fr7 = fr & 7;

    const int rl = tid >> 3;           // row within 64-row round
    const int sl = tid & 7;
    const int ss = sl ^ (rl & 7);      // T2 pre-swizzled source slot

    floatx4 acc[4][2] = {};

    // stage A/B: 128x64 tile = 2 rounds each
    auto stageA = [&](int k0, bf16* Ld) {
        #pragma unroll
        for (int c = 0; c < 2; ++c) {
            const bf16* src = A + (size_t)(row0 + c * 64 + rl) * LDA + k0 + ss * 8;
            __builtin_amdgcn_global_load_lds((const GLOBAL_AS void*)src,
                (LDS_AS void*)(Ld + c * 4096 + wave * 512), 16, 0, 0);
        }
    };
    auto stageB = [&](int k0, bf16* Ld) {
        #pragma unroll
        for (int c = 0; c < 2; ++c) {
            const bf16* src = W + (size_t)(col0 + c * 64 + rl) * K + k0 + ss * 8;
            __builtin_amdgcn_global_load_lds((const GLOBAL_AS void*)src,
                (LDS_AS void*)(Ld + c * 4096 + wave * 512), 16, 0, 0);
        }
    };

    bf16x8 afA[4][2], bb[2][2];

    auto loadA = [&](const bf16* Ab) {
        #pragma unroll
        for (int ii = 0; ii < 4; ++ii)
            #pragma unroll
            for (int kk = 0; kk < 2; ++kk)
                afA[ii][kk] = *(const bf16x8*)(Ab
                    + (wm + ii * 16 + fr) * 64
                    + (((kk * 4 + fks) ^ fr7) * 8));
    };
    auto loadB = [&](const bf16* Bb) {
        #pragma unroll
        for (int jj = 0; jj < 2; ++jj)
            #pragma unroll
            for (int kk = 0; kk < 2; ++kk)
                bb[jj][kk] = *(const bf16x8*)(Bb
                    + (wn + jj * 16 + fr) * 64
                    + (((kk * 4 + fks) ^ fr7) * 8));
    };
    auto mfmaH = [&](int qi) {         // rows qi..qi+1 x cols 0-1, 8 MFMA
        __builtin_amdgcn_s_setprio(1);
        #pragma unroll
        for (int ii = 0; ii < 2; ++ii)
            #pragma unroll
            for (int jj = 0; jj < 2; ++jj)
                #pragma unroll
                for (int kk = 0; kk < 2; ++kk)
                    acc[qi + ii][jj] = __builtin_amdgcn_mfma_f32_16x16x32_bf16(
                        afA[qi + ii][kk], bb[jj][kk], acc[qi + ii][jj], 0, 0, 0);
        __builtin_amdgcn_s_setprio(0);
        hard_barrier();
    };

    stageA(0, lds[0]);
    stageB(0, lds[0] + 128 * 64);

    for (int t = 0; t < NT; ++t) {
        const int buf = t & 1;
        const bf16* Ab = lds[buf];
        const bf16* Bb = lds[buf] + 128 * 64;
        asm volatile("s_waitcnt lgkmcnt(0)" ::: "memory");
        if (t + 1 < NT) {
            stageA((t + 1) * 64, lds[buf ^ 1]);
            stageB((t + 1) * 64, lds[buf ^ 1] + 128 * 64);
            asm volatile("s_waitcnt vmcnt(4)" ::: "memory"); // tile t's 4 done
        } else {
            asm volatile("s_waitcnt vmcnt(0)" ::: "memory");
        }
        hard_barrier();

        loadA(Ab);
        loadB(Bb);
        mfmaH(0);           // phase 0: rows 0-1 x cols 0-1
        mfmaH(2);           // phase 1: rows 2-3 x cols 0-1
    }

    const int fc  = lane & 15;
    const int fr4 = (lane >> 4) * 4;
    #pragma unroll
    for (int i = 0; i < 4; ++i)
        #pragma unroll
        for (int j = 0; j < 2; ++j) {
            const int col = col0 + wn + j * 16 + fc;
            const float b = bias ? bias[col] : 0.0f;
            #pragma unroll
            for (int r = 0; r < 4; ++r) {
                const int row = row0 + wm + i * 16 + fr4 + r;
                C[(size_t)row * LDC + col] = (CT)(acc[i][j][r] + b);
            }
        }
}

// ---------------------------------------------------------------------------
// R6-proven f32-capable GEMM (non-pipelined) — fallback path only.
// ---------------------------------------------------------------------------
template<typename CT, bool AF32, bool WF32, int TM, int M, int N, int K,
         int LDA, int LDC>
__global__ __launch_bounds__(256, 2)
void gemm_bt(const void* __restrict__ Av, const void* __restrict__ Wv,
             CT* __restrict__ C, const float* __restrict__ bias)
{
    constexpr int MI = TM / 32;
    __shared__ __align__(16) bf16 As[TM * 32];
    __shared__ __align__(16) bf16 Bs[128 * 32];

    const int tid  = threadIdx.x;
    const int lane = tid & 63;
    const int wave = tid >> 6;

    const int lin = blockIdx.y * gridDim.x + blockIdx.x;
    const int ch  = gridDim.x >> 3;
    const int xcd = lin & 7;
    const int rr  = lin >> 3;
    const int bx  = xcd * ch + (rr % ch);
    const int by  = rr / ch;

    const int row0 = bx * TM;
    const int col0 = by * 128;

    const int wm = (wave & 1) * (TM / 2);
    const int wn = (wave >> 1) * 64;

    floatx4 acc[MI][4] = {};

    const int fr = lane & 15;
    const int fk = (lane >> 4) * 8;

    const int lr = lane >> 2;
    const int lk = (lane & 3) * 8;

    for (int k0 = 0; k0 < K; k0 += 32) {
        if (AF32) {
            constexpr int NV = TM * 4;
            #pragma unroll
            for (int c = 0; c < NV / 256; ++c) {
                const int idx = tid + c * 256;
                const int r   = idx >> 2;
                const int cb  = (idx & 3) * 8;
                const float4* g = (const float4*)((const float*)Av
                                   + (size_t)(row0 + r) * LDA + k0 + cb);
                float4 g0 = g[0], g1 = g[1];
                bf16x8 va;
                va[0]=(bf16)g0.x; va[1]=(bf16)g0.y; va[2]=(bf16)g0.z; va[3]=(bf16)g0.w;
                va[4]=(bf16)g1.x; va[5]=(bf16)g1.y; va[6]=(bf16)g1.z; va[7]=(bf16)g1.w;
                *(bf16x8*)(As + r * 32 + cb) = va;
            }
        } else {
            constexpr int CAW = TM / 64;
            #pragma unroll
            for (int c = 0; c < CAW; ++c) {
                const int chunk = wave * CAW + c;
                const int r = chunk * 16 + lr;
                const bf16* gA = (const bf16*)Av + (size_t)(row0 + r) * LDA + k0 + lk;
                __builtin_amdgcn_global_load_lds((const GLOBAL_AS void*)gA,
                                                 (LDS_AS void*)(As + chunk * 512),
                                                 16, 0, 0);
            }
        }
        if (WF32) {
            #pragma unroll
            for (int c = 0; c < 2; ++c) {
                const int idx = tid + c * 256;
                const int r   = idx >> 2;
                const int cb  = (idx & 3) * 8;
                const float4* g = (const float4*)((const float*)Wv
                                   + (size_t)(col0 + r) * K + k0 + cb);
                float4 g0 = g[0], g1 = g[1];
                bf16x8 vw;
                vw[0]=(bf16)g0.x; vw[1]=(bf16)g0.y; vw[2]=(bf16)g0.z; vw[3]=(bf16)g0.w;
                vw[4]=(bf16)g1.x; vw[5]=(bf16)g1.y; vw[6]=(bf16)g1.z; vw[7]=(bf16)g1.w;
                *(bf16x8*)(Bs + r * 32 + cb) = vw;
            }
        } else {
            #pragma unroll
            for (int c = 0; c < 2; ++c) {
                const int chunk = wave * 2 + c;
                const int r = chunk * 16 + lr;
                const bf16* gB = (const bf16*)Wv + (size_t)(col0 + r) * K + k0 + lk;
                __builtin_amdgcn_global_load_lds((const GLOBAL_AS void*)gB,
                                                 (LDS_AS void*)(Bs + chunk * 512),
                                                 16, 0, 0);
            }
        }
        __syncthreads();

        bf16x8 af[MI], bfr[4];
        #pragma unroll
        for (int i = 0; i < MI; ++i)
            af[i]  = *(const bf16x8*)(As + (wm + i * 16 + fr) * 32 + fk);
        #pragma unroll
        for (int j = 0; j < 4; ++j)
            bfr[j] = *(const bf16x8*)(Bs + (wn + j * 16 + fr) * 32 + fk);
        #pragma unroll
        for (int i = 0; i < MI; ++i)
            #pragma unroll
            for (int j = 0; j < 4; ++j)
                acc[i][j] = __builtin_amdgcn_mfma_f32_16x16x32_bf16(
                    af[i], bfr[j], acc[i][j], 0, 0, 0);

        __syncthreads();
    }

    const int fc  = lane & 15;
    const int fr4 = (lane >> 4) * 4;
    #pragma unroll
    for (int i = 0; i < MI; ++i) {
        #pragma unroll
        for (int j = 0; j < 4; ++j) {
            const int col = col0 + wn + j * 16 + fc;
            const float b = bias ? bias[col] : 0.0f;
            #pragma unroll
            for (int r = 0; r < 4; ++r) {
                const int row = row0 + wm + i * 16 + fr4 + r;
                C[(size_t)row * LDC + col] = (CT)(acc[i][j][r] + b);
            }
        }
    }
}

// ---------------------------------------------------------------------------
// MFMA local-window attention (R11 verified). One wave per (b,h,16-row tile).
// Wave-private LDS (no block barriers), direct-K fragments, XOR-swizzled Vt,
// XCD-swizzled block index.
// ---------------------------------------------------------------------------
__global__ __launch_bounds__(256)
void attn_tile(const bf16* __restrict__ qkv, bf16* __restrict__ aout)
{
    __shared__ __align__(16) bf16 Vt[4][64][40];
    __shared__ __align__(16) bf16 Ps[4][16][40];

    const int w    = threadIdx.x >> 6;
    const int lane = threadIdx.x & 63;
    const int c    = lane & 15;
    const int q    = lane >> 4;
    int bid = blockIdx.x;
    bid = (bid & 7) * 96 + (bid >> 3);     // XCD swizzle, 768 = 8*96, bijective
    const int wid  = bid * 4 + w;          // 0..3071
    const int it   = wid & 127;
    const int bh   = wid >> 7;             // 0..23
    const int h    = bh % 12;
    const int b    = bh / 12;
    const int I0   = it * 16;
    const int bbase = b * 2048;
    const int j0   = I0 - 7;

    // ---- V staging: transposed into Vt[d][j], XOR-swizzled columns ----
    #pragma unroll
    for (int itr = 0; itr < 4; ++itr) {
        int idx = itr * 64 + lane;        // 0..255
        int row = idx >> 3;               // j: 0..31
        int dc  = (idx & 7) * 8;          // d block: 0,8,...,56
        int jc  = j0 + row; jc = jc < 0 ? 0 : (jc > 2047 ? 2047 : jc);
        const bf16* base = qkv + (size_t)(bbase + jc) * 2304 + 1536 + h * 64 + dc;
        bf16x8 vv = *(const bf16x8*)base;
        #pragma unroll
        for (int e = 0; e < 8; ++e) {
            int d    = dc + e;
            int col2 = (row * 2) ^ (((d >> 3) & 3) << 4);   // swizzled byte col
            *(bf16*)((char*)&Vt[w][d][0] + col2) = vv[e];
        }
    }

    // ---- Q fragments (direct) ----
    const bf16* qrow = qkv + (size_t)(bbase + I0 + c) * 2304 + h * 64;
    bf16x8 aq0 = *(const bf16x8*)(qrow + q * 8);
    bf16x8 aq1 = *(const bf16x8*)(qrow + 32 + q * 8);

    // ---- QK^T with K B-fragments loaded directly from global ----
    floatx4 st[2] = {};
    #pragma unroll
    for (int t = 0; t < 2; ++t) {
        int jr = j0 + t * 16 + c;
        jr = jr < 0 ? 0 : (jr > 2047 ? 2047 : jr);
        const bf16* krow = qkv + (size_t)(bbase + jr) * 2304 + 768 + h * 64;
        bf16x8 k0 = *(const bf16x8*)(krow + q * 8);
        bf16x8 k1 = *(const bf16x8*)(krow + 32 + q * 8);
        st[t] = __builtin_amdgcn_mfma_f32_16x16x32_bf16(aq0, k0, st[t], 0, 0, 0);
        st[t] = __builtin_amdgcn_mfma_f32_16x16x32_bf16(aq1, k1, st[t], 0, 0, 0);
    }

    float s[2][4];
    #pragma unroll
    for (int t = 0; t < 2; ++t)
        #pragma unroll
        for (int r = 0; r < 4; ++r) {
            int il = q * 4 + r;
            int jl = t * 16 + c;
            int ja = j0 + jl;
            bool valid = (jl >= il) && (jl <= il + 14) && (ja >= 0) && (ja < 2048);
            s[t][r] = valid ? st[t][r] * 0.125f : -1e30f;
        }

    float l[4], p[2][4];
    #pragma unroll
    for (int r = 0; r < 4; ++r) {
        float m2 = fmaxf(s[0][r], s[1][r]);
        #pragma unroll
        for (int mk = 1; mk < 16; mk <<= 1) m2 = fmaxf(m2, __shfl_xor(m2, mk, 64));
        p[0][r] = __expf(s[0][r] - m2);
        p[1][r] = __expf(s[1][r] - m2);
        float l2 = p[0][r] + p[1][r];
        #pragma unroll
        for (int mk = 1; mk < 16; mk <<= 1) l2 += __shfl_xor(l2, mk, 64);
        l[r] = l2;
    }

    // ---- P exchange (wave-private LDS, no block barrier needed) ----
    #pragma unroll
    for (int r = 0; r < 4; ++r) {
        Ps[w][q * 4 + r][c]      = (bf16)p[0][r];
        Ps[w][q * 4 + r][16 + c] = (bf16)p[1][r];
    }

    bf16x8 ap = *(const bf16x8*)(&Ps[w][c][q * 8]);
    floatx4 ov[4];
    #pragma unroll
    for (int nt = 0; nt < 4; ++nt) {
        int dr = nt * 16 + c;
        int cb = (q * 16) ^ (((dr >> 3) & 3) << 4);         // match write swizzle
        bf16x8 vf = *(const bf16x8*)((const char*)&Vt[w][dr][0] + cb);
        floatx4 z = {};
        ov[nt] = __builtin_amdgcn_mfma_f32_16x16x32_bf16(ap, vf, z, 0, 0, 0);
    }

    float rl[4];
    #pragma unroll
    for (int r = 0; r < 4; ++r) rl[r] = 1.0f / l[r];
    #pragma unroll
    for (int r = 0; r < 4; ++r) {
        bf16* orow = aout + (size_t)(bbase + I0 + q * 4 + r) * 768 + h * 64;
        #pragma unroll
        for (int nt = 0; nt < 4; ++nt)
            orow[nt * 16 + c] = (bf16)(ov[nt][r] * rl[r]);
    }
}

// ---------------------------------------------------------------------------
extern "C" void kernel_launch(void* const* d_in, const int* in_sizes, int n_in,
                              void* d_out, int out_size, void* d_ws, size_t ws_size,
                              hipStream_t stream)
{
    const float* x      = (const float*)d_in[0];  // [4096][768] f32
    const float* w_qkv  = (const float*)d_in[1];  // [2304][768] f32
    const float* w_proj = (const float*)d_in[2];  // [768][768]  f32
    const float* b_proj = (const float*)d_in[3];  // [768]       f32
    float* out = (float*)d_out;                   // [4096][768] f32

    bf16* qkv = (bf16*)d_ws;                      // [4096][2304] bf16, 18.87 MB
    const size_t QKV_B  = (size_t)4096 * 2304 * 2;
    const size_t AO_B   = (size_t)4096 * 768 * 2; // 6.29 MB
    const size_t XB_B   = (size_t)4096 * 768 * 2;
    const size_t WQKV_B = (size_t)2304 * 768 * 2;
    const size_t WPRJ_B = (size_t)768 * 768 * 2;

    if (ws_size >= QKV_B + AO_B + XB_B + WQKV_B + WPRJ_B) {
        // main path: cvt3 + 256x192 GEMM1 + attn + 128x128 GEMM2 (all
        // single-round grids, counted-vmcnt phase-split)
        bf16* aout = (bf16*)((char*)d_ws + QKV_B);
        bf16* xb   = (bf16*)((char*)aout + AO_B);
        bf16* wqb  = (bf16*)((char*)xb + XB_B);
        bf16* wpb  = (bf16*)((char*)wqb + WQKV_B);

        const int n0 = 4096 * 768 / 4, n1 = 2304 * 768 / 4, n2 = 768 * 768 / 4;
        cvt3_f32_bf16<<<dim3((n0 + n1 + n2) / 256), 256, 0, stream>>>(
            x, w_qkv, w_proj, xb, wqb, wpb, n0, n1, n2);

        // 1) qkv = xb @ wqb^T   (256x192 phase-split, 192 blocks x 512 thr)
        gemm8p_bt<bf16, 4096, 2304, 768, 768, 2304>
            <<<dim3(192), 512, 0, stream>>>(xb, wqb, qkv);

        // 2) attention -> dense [4096][768]
        attn_tile<<<dim3(768), 256, 0, stream>>>(qkv, aout);

        // 3) out = aout @ wpb^T + b_proj (128x128 phase-split, 192 blocks)
        gemm8p2_bt<float, 4096, 768, 768, 768, 768>
            <<<dim3(192), 512, 0, stream>>>(aout, wpb, out, b_proj);
    } else {
        // fallback: f32 cvt inside GEMM staging (R6-proven), minimal ws
        gemm_bt<bf16, true, true, 128, 4096, 2304, 768, 768, 2304>
            <<<dim3(32, 18), 256, 0, stream>>>(x, w_qkv, qkv, nullptr);

        bf16* aout = (bf16*)((char*)d_ws + QKV_B);
        attn_tile<<<dim3(768), 256, 0, stream>>>(qkv, aout);

        gemm_bt<float, false, true, 64, 4096, 768, 768, 768, 768>
            <<<dim3(64, 6), 256, 0, stream>>>(aout, w_proj, out, b_proj);
    }
}